// Round 1
// baseline (100.814 us; speedup 1.0000x reference)
//
#include <hip/hip_runtime.h>

#define NPSI 256
#define MM 8
#define KK 4

__global__ __launch_bounds__(256) void eik_kernel(
    const float* __restrict__ t_ptr,
    const float* __restrict__ psi_a,
    const float* __restrict__ theta_a,
    const float* __restrict__ varphi_a,
    const float* __restrict__ q_vals,
    const float* __restrict__ theta0_a,
    const float* __restrict__ omega_a,
    const float* __restrict__ psi0_a,
    const float* __restrict__ psi_scale_a,
    const float* __restrict__ alpha_scale_a,
    const float* __restrict__ gh_a,        // [M,4,6]
    const int*   __restrict__ n_a,
    float* __restrict__ out,               // [2*N]: phi then apar
    int N)
{
    int idx = blockIdx.x * blockDim.x + threadIdx.x;
    if (idx >= N) return;

    const float t      = t_ptr[0];
    const float psi    = psi_a[idx];
    const float theta  = theta_a[idx];
    const float varphi = varphi_a[idx];

    // ---- cubic Hermite interpolation of q_vals at psi (index units) ----
    // u = psi/H = psi*(NPSI-1); slopes = jnp.gradient(f) (already in index units
    // because ref does (gradient/H)*H).
    float u = psi * (float)(NPSI - 1);
    int   i = (int)floorf(u);
    i = min(max(i, 0), NPSI - 2);
    float s  = u - (float)i;
    float f0 = q_vals[i];
    float f1 = q_vals[i + 1];
    float d0 = (i == 0)        ? (f1 - f0) : 0.5f * (f1 - q_vals[i - 1]);
    float d1 = (i == NPSI - 2) ? (f1 - f0) : 0.5f * (q_vals[i + 2] - f0);
    float s2 = s * s, s3 = s2 * s;
    float q  = (2.f * s3 - 3.f * s2 + 1.f) * f0
             + (s3 - 2.f * s2 + s)         * d0
             + (-2.f * s3 + 3.f * s2)      * f1
             + (s3 - s2)                   * d1;

    // NOTE: alpha0 = cubic_interp(q_vals*theta0_m + aoff_vals) = q*theta0_m + aoff
    // (interp is linear in f), so y = q*(theta + 2*pi*k - theta0_m)/alpha_scale_m
    // and aoff cancels entirely -> no aoff interpolation needed.

    const float TWO_PI = 6.28318530717958647692f;
    float phi = 0.f, apar = 0.f;

    for (int m = 0; m < MM; ++m) {
        // wave-uniform (scalar) loads
        const float theta0 = theta0_a[m];
        const float omega  = omega_a[m];
        const float psi0   = psi0_a[m];
        const float ps     = psi_scale_a[m];
        const float as     = alpha_scale_a[m];
        const float nf     = (float)n_a[m];
        const float* c     = gh_a + m * 24;

        const float x   = (psi - psi0) / ps;
        const float gx  = __expf(-0.5f * x * x);
        const float h20 = 4.f * x * x - 2.f;

        const float dth    = theta - theta0;
        const float y0     = q * dth / as;
        const float dy     = q * TWO_PI / as;
        const float phase0 = omega * t - nf * varphi + nf * (q * dth);
        const float dph    = TWO_PI * (nf * q);

        // hoist x-only polynomial parts out of the k loop
        float pa[4], pb[4], pc5[4];
        #pragma unroll
        for (int comp = 0; comp < 4; ++comp) {
            const float* cc = c + comp * 6;
            pa[comp]  = cc[0] + cc[1] * x + cc[3] * h20;
            pb[comp]  = cc[2] + cc[4] * x;
            pc5[comp] = cc[5];
        }

        #pragma unroll
        for (int k = 0; k < KK; ++k) {
            const float kf    = (float)k;
            const float y     = y0 + kf * dy;
            const float h02   = 4.f * y * y - 2.f;
            const float g     = gx * __expf(-0.5f * y * y);
            const float phase = phase0 + kf * dph;
            float sp, cp;
            __sincosf(phase, &sp, &cp);
            const float gc = g * cp;
            const float gs = g * sp;
            const float p0 = pa[0] + pb[0] * y + pc5[0] * h02;
            const float p1 = pa[1] + pb[1] * y + pc5[1] * h02;
            const float p2 = pa[2] + pb[2] * y + pc5[2] * h02;
            const float p3 = pa[3] + pb[3] * y + pc5[3] * h02;
            phi  += p0 * gc - p1 * gs;
            apar += p2 * gc - p3 * gs;
        }
    }

    out[idx]     = phi;
    out[idx + N] = apar;
}

extern "C" void kernel_launch(void* const* d_in, const int* in_sizes, int n_in,
                              void* d_out, int out_size, void* d_ws, size_t ws_size,
                              hipStream_t stream) {
    // setup_inputs order:
    // 0:t 1:psi 2:theta 3:varphi 4:q_vals 5:aoff_vals 6:theta0 7:omega
    // 8:psi0 9:psi_scale 10:alpha_scale 11:gh_coefs 12:n
    const float* t       = (const float*)d_in[0];
    const float* psi     = (const float*)d_in[1];
    const float* theta   = (const float*)d_in[2];
    const float* varphi  = (const float*)d_in[3];
    const float* q_vals  = (const float*)d_in[4];
    const float* theta0  = (const float*)d_in[6];
    const float* omega   = (const float*)d_in[7];
    const float* psi0    = (const float*)d_in[8];
    const float* psc     = (const float*)d_in[9];
    const float* asc     = (const float*)d_in[10];
    const float* gh      = (const float*)d_in[11];
    const int*   n_arr   = (const int*)d_in[12];

    const int N = in_sizes[1];
    float* out = (float*)d_out;

    const int block = 256;
    const int grid  = (N + block - 1) / block;
    eik_kernel<<<grid, block, 0, stream>>>(t, psi, theta, varphi, q_vals,
                                           theta0, omega, psi0, psc, asc,
                                           gh, n_arr, out, N);
}

// Round 2
// 96.646 us; speedup vs baseline: 1.0431x; 1.0431x over previous
//
#include <hip/hip_runtime.h>

#define NPSI 256
#define MM 8
#define KK 4

__global__ __launch_bounds__(256) void eik_kernel(
    const float* __restrict__ t_ptr,
    const float* __restrict__ psi_a,
    const float* __restrict__ theta_a,
    const float* __restrict__ varphi_a,
    const float* __restrict__ q_vals,
    const float* __restrict__ theta0_a,
    const float* __restrict__ omega_a,
    const float* __restrict__ psi0_a,
    const float* __restrict__ psi_scale_a,
    const float* __restrict__ alpha_scale_a,
    const float* __restrict__ gh_a,        // [M,4,6]
    const int*   __restrict__ n_a,
    float* __restrict__ out,               // [2*N]: phi then apar
    int N)
{
    int idx = blockIdx.x * blockDim.x + threadIdx.x;
    if (idx >= N) return;

    const float t      = t_ptr[0];
    const float psi    = psi_a[idx];
    const float theta  = theta_a[idx];
    const float varphi = varphi_a[idx];

    // ---- cubic Hermite interpolation of q_vals at psi (index units) ----
    // (gradient/H * H cancels -> slopes in index units)
    float u = psi * (float)(NPSI - 1);
    int   i = (int)floorf(u);
    i = min(max(i, 0), NPSI - 2);
    float s  = u - (float)i;
    float f0 = q_vals[i];
    float f1 = q_vals[i + 1];
    float d0 = (i == 0)        ? (f1 - f0) : 0.5f * (f1 - q_vals[i - 1]);
    float d1 = (i == NPSI - 2) ? (f1 - f0) : 0.5f * (q_vals[i + 2] - f0);
    float s2 = s * s, s3 = s2 * s;
    float q  = (2.f * s3 - 3.f * s2 + 1.f) * f0
             + (s3 - 2.f * s2 + s)         * d0
             + (-2.f * s3 + 3.f * s2)      * f1
             + (s3 - s2)                   * d1;

    // alpha0 = cubic_interp(q_vals*theta0_m + aoff_vals) = q*theta0_m + aoff
    // (interp linear in f) -> aoff cancels in y; only q needed.

    const float TWO_PI = 6.28318530717958647692f;
    float phi = 0.f, apar = 0.f;

    // keep the m loop ROLLED: full unroll hoists ~200 param loads and spills
    #pragma unroll 1
    for (int m = 0; m < MM; ++m) {
        // wave-uniform loads (compiler scalarizes: s_load)
        const float theta0 = theta0_a[m];
        const float omega  = omega_a[m];
        const float psi0   = psi0_a[m];
        const float inv_ps = __builtin_amdgcn_rcpf(psi_scale_a[m]);
        const float inv_as = __builtin_amdgcn_rcpf(alpha_scale_a[m]);
        const float nf     = (float)n_a[m];
        const float* c     = gh_a + m * 24;

        const float x   = (psi - psi0) * inv_ps;
        const float x2  = x * x;
        const float gx  = __expf(-0.5f * x2);
        const float h20 = 4.f * x2 - 2.f;

        const float dth  = theta - theta0;
        const float qdth = q * dth;
        float y  = qdth * inv_as;                 // y at k=0
        const float dy = (q * TWO_PI) * inv_as;   // y step per k

        const float phase0 = fmaf(omega, t, fmaf(nf, qdth, -nf * varphi));
        const float dph    = TWO_PI * (nf * q);

        // 2 sincos per m + 4-FMA rotation per k (instead of 4 sincos)
        float cp = __cosf(phase0), sp = __sinf(phase0);
        const float cd = __cosf(dph), sd = __sinf(dph);

        // hoist x-only polynomial parts out of the k loop
        float pa[4], pb[4], pc5[4];
        #pragma unroll
        for (int comp = 0; comp < 4; ++comp) {
            pa[comp]  = fmaf(c[comp*6+3], h20, fmaf(c[comp*6+1], x, c[comp*6+0]));
            pb[comp]  = fmaf(c[comp*6+4], x, c[comp*6+2]);
            pc5[comp] = c[comp*6+5];
        }

        #pragma unroll
        for (int k = 0; k < KK; ++k) {
            const float y2  = y * y;
            const float g   = gx * __expf(-0.5f * y2);
            const float h02 = fmaf(4.f, y2, -2.f);
            const float gc  = g * cp;
            const float gs  = g * sp;
            const float p0 = fmaf(pc5[0], h02, fmaf(pb[0], y, pa[0]));
            const float p1 = fmaf(pc5[1], h02, fmaf(pb[1], y, pa[1]));
            const float p2 = fmaf(pc5[2], h02, fmaf(pb[2], y, pa[2]));
            const float p3 = fmaf(pc5[3], h02, fmaf(pb[3], y, pa[3]));
            phi  = fmaf(p0, gc, phi);
            phi  = fmaf(-p1, gs, phi);
            apar = fmaf(p2, gc, apar);
            apar = fmaf(-p3, gs, apar);
            // rotate (cp,sp) by dph; advance y
            const float ncp = fmaf(cp, cd, -sp * sd);
            const float nsp = fmaf(sp, cd,  cp * sd);
            cp = ncp; sp = nsp;
            y += dy;
        }
    }

    out[idx]     = phi;
    out[idx + N] = apar;
}

extern "C" void kernel_launch(void* const* d_in, const int* in_sizes, int n_in,
                              void* d_out, int out_size, void* d_ws, size_t ws_size,
                              hipStream_t stream) {
    // 0:t 1:psi 2:theta 3:varphi 4:q_vals 5:aoff_vals 6:theta0 7:omega
    // 8:psi0 9:psi_scale 10:alpha_scale 11:gh_coefs 12:n
    const float* t       = (const float*)d_in[0];
    const float* psi     = (const float*)d_in[1];
    const float* theta   = (const float*)d_in[2];
    const float* varphi  = (const float*)d_in[3];
    const float* q_vals  = (const float*)d_in[4];
    const float* theta0  = (const float*)d_in[6];
    const float* omega   = (const float*)d_in[7];
    const float* psi0    = (const float*)d_in[8];
    const float* psc     = (const float*)d_in[9];
    const float* asc     = (const float*)d_in[10];
    const float* gh      = (const float*)d_in[11];
    const int*   n_arr   = (const int*)d_in[12];

    const int N = in_sizes[1];
    float* out = (float*)d_out;

    const int block = 256;
    const int grid  = (N + block - 1) / block;
    eik_kernel<<<grid, block, 0, stream>>>(t, psi, theta, varphi, q_vals,
                                           theta0, omega, psi0, psc, asc,
                                           gh, n_arr, out, N);
}

// Round 3
// 96.158 us; speedup vs baseline: 1.0484x; 1.0051x over previous
//
#include <hip/hip_runtime.h>

#define NPSI 256
#define MM 8
#define KK 4

#if __has_builtin(__builtin_amdgcn_exp2f)
#define EXP2F(x) __builtin_amdgcn_exp2f(x)
#else
#define EXP2F(x) exp2f(x)
#endif

// hardware v_sin/v_cos take input in REVOLUTIONS (sin(2*pi*x)), valid |x|<=256
#define SIN_REV(x) __builtin_amdgcn_sinf(x)
#define COS_REV(x) __builtin_amdgcn_cosf(x)

__global__ __launch_bounds__(256) void eik_kernel(
    const float* __restrict__ t_ptr,
    const float* __restrict__ psi_a,
    const float* __restrict__ theta_a,
    const float* __restrict__ varphi_a,
    const float* __restrict__ q_vals,
    const float* __restrict__ theta0_a,
    const float* __restrict__ omega_a,
    const float* __restrict__ psi0_a,
    const float* __restrict__ psi_scale_a,
    const float* __restrict__ alpha_scale_a,
    const float* __restrict__ gh_a,        // [M,4,6]
    const int*   __restrict__ n_a,
    float* __restrict__ out,               // [2*N]: phi then apar
    int N)
{
    int idx = blockIdx.x * blockDim.x + threadIdx.x;
    if (idx >= N) return;

    const float INV2PI = 0.15915494309189533577f;
    const float TWO_PI = 6.28318530717958647692f;
    const float NEXPC  = -0.72134752044448170368f; // -0.5*log2(e)

    const float t      = t_ptr[0];
    const float psi    = psi_a[idx];
    const float theta  = theta_a[idx];
    const float varphi = varphi_a[idx];

    // ---- cubic Hermite interpolation of q_vals at psi ----
    // slopes in index units (ref's gradient/H * H cancels)
    float u = psi * (float)(NPSI - 1);
    int   i = (int)floorf(u);
    i = min(max(i, 0), NPSI - 2);
    float s  = u - (float)i;
    float f0 = q_vals[i];
    float f1 = q_vals[i + 1];
    float d0 = (i == 0)        ? (f1 - f0) : 0.5f * (f1 - q_vals[i - 1]);
    float d1 = (i == NPSI - 2) ? (f1 - f0) : 0.5f * (q_vals[i + 2] - f0);
    float s2 = s * s, s3 = s2 * s;
    float q  = (2.f * s3 - 3.f * s2 + 1.f) * f0
             + (s3 - 2.f * s2 + s)         * d0
             + (-2.f * s3 + 3.f * s2)      * f1
             + (s3 - s2)                   * d1;

    // alpha0 = cubic_interp(q_vals*theta0 + aoff_vals) = q*theta0 + aoff
    // (interp is linear in f) -> aoff cancels in y; only q needed.

    // per-thread hoists
    const float q2pi = q * TWO_PI;        // for dy
    const float tt   = t * INV2PI;        // t in revolutions
    const float v2p  = varphi * INV2PI;   // varphi in revolutions

    float phi = 0.f, apar = 0.f;

    #pragma unroll 2
    for (int m = 0; m < MM; ++m) {
        const float theta0 = theta0_a[m];
        const float omega  = omega_a[m];
        const float psi0   = psi0_a[m];
        const float inv_ps = __builtin_amdgcn_rcpf(psi_scale_a[m]);
        const float inv_as = __builtin_amdgcn_rcpf(alpha_scale_a[m]);
        const float nf     = (float)n_a[m];
        const float* c     = gh_a + m * 24;

        const float x  = (psi - psi0) * inv_ps;
        const float x2 = x * x;
        const float x4 = 4.f * x2;

        // folded GH coefficients:
        // p = (c0-2c3-2c5) + c1*x + c3*(4x^2) + (c2+c4*x)*y + c5*(4y^2)
        float pa[4], pb[4], pf[4];
        #pragma unroll
        for (int comp = 0; comp < 4; ++comp) {
            const float c0 = c[comp*6+0], c1 = c[comp*6+1], c2 = c[comp*6+2];
            const float c3 = c[comp*6+3], c4 = c[comp*6+4], c5 = c[comp*6+5];
            const float ssum = c3 + c5;
            const float a0   = fmaf(-2.f, ssum, c0);       // c0-2c3-2c5
            pa[comp] = fmaf(c3, x4, fmaf(c1, x, a0));      // + c1 x + 4c3 x^2
            pb[comp] = fmaf(c4, x, c2);
            pf[comp] = c5;                                  // * 4y^2
        }

        const float dth    = theta - theta0;
        const float qdth   = q * dth;
        const float y0     = qdth * inv_as;
        const float dy     = q2pi * inv_as;
        const float dphrev = nf * q;                        // phase step per k, in revolutions
        // phase0 in revolutions: (omega*t - nf*varphi + nf*q*dth) / 2pi
        const float base    = fmaf(omega, tt, -nf * v2p);
        const float p0rev   = fmaf(nf, qdth * INV2PI, base);

        #pragma unroll
        for (int k = 0; k < KK; ++k) {
            const float kf = (float)k;
            const float y  = fmaf(kf, dy, y0);
            const float ph = fmaf(kf, dphrev, p0rev);
            const float sp = SIN_REV(ph);
            const float cp = COS_REV(ph);
            const float t2 = fmaf(y, y, x2);          // x^2 + y^2
            const float y4 = fmaf(4.f, t2, -x4);      // 4y^2
            const float g  = EXP2F(t2 * NEXPC);       // exp(-0.5(x^2+y^2))
            const float gc = g * cp;
            const float gs = g * sp;
            const float p0 = fmaf(pf[0], y4, fmaf(pb[0], y, pa[0]));
            const float p1 = fmaf(pf[1], y4, fmaf(pb[1], y, pa[1]));
            const float p2 = fmaf(pf[2], y4, fmaf(pb[2], y, pa[2]));
            const float p3 = fmaf(pf[3], y4, fmaf(pb[3], y, pa[3]));
            phi  = fmaf(p0, gc, phi);
            phi  = fmaf(-p1, gs, phi);
            apar = fmaf(p2, gc, apar);
            apar = fmaf(-p3, gs, apar);
        }
    }

    out[idx]     = phi;
    out[idx + N] = apar;
}

extern "C" void kernel_launch(void* const* d_in, const int* in_sizes, int n_in,
                              void* d_out, int out_size, void* d_ws, size_t ws_size,
                              hipStream_t stream) {
    // 0:t 1:psi 2:theta 3:varphi 4:q_vals 5:aoff_vals 6:theta0 7:omega
    // 8:psi0 9:psi_scale 10:alpha_scale 11:gh_coefs 12:n
    const float* t       = (const float*)d_in[0];
    const float* psi     = (const float*)d_in[1];
    const float* theta   = (const float*)d_in[2];
    const float* varphi  = (const float*)d_in[3];
    const float* q_vals  = (const float*)d_in[4];
    const float* theta0  = (const float*)d_in[6];
    const float* omega   = (const float*)d_in[7];
    const float* psi0    = (const float*)d_in[8];
    const float* psc     = (const float*)d_in[9];
    const float* asc     = (const float*)d_in[10];
    const float* gh      = (const float*)d_in[11];
    const int*   n_arr   = (const int*)d_in[12];

    const int N = in_sizes[1];
    float* out = (float*)d_out;

    const int block = 256;
    const int grid  = (N + block - 1) / block;
    eik_kernel<<<grid, block, 0, stream>>>(t, psi, theta, varphi, q_vals,
                                           theta0, omega, psi0, psc, asc,
                                           gh, n_arr, out, N);
}

// Round 4
// 92.370 us; speedup vs baseline: 1.0914x; 1.0410x over previous
//
#include <hip/hip_runtime.h>

#define NPSI 256
#define MM 8
#define KK 4

typedef float v2f __attribute__((ext_vector_type(2)));

#if __has_builtin(__builtin_amdgcn_exp2f)
#define EXP2F(x) __builtin_amdgcn_exp2f(x)
#else
#define EXP2F(x) exp2f(x)
#endif
// hardware v_sin/v_cos take REVOLUTIONS (sin(2*pi*x)), valid |x|<=256
#define SIN_REV(x) __builtin_amdgcn_sinf(x)
#define COS_REV(x) __builtin_amdgcn_cosf(x)

#define VFMA(a,b,c) __builtin_elementwise_fma((v2f)(a),(v2f)(b),(v2f)(c))

__device__ inline float cubic_q(const float* __restrict__ q_vals, float psi) {
    float u = psi * (float)(NPSI - 1);
    int   i = (int)floorf(u);
    i = min(max(i, 0), NPSI - 2);
    float s  = u - (float)i;
    float f0 = q_vals[i];
    float f1 = q_vals[i + 1];
    float d0 = (i == 0)        ? (f1 - f0) : 0.5f * (f1 - q_vals[i - 1]);
    float d1 = (i == NPSI - 2) ? (f1 - f0) : 0.5f * (q_vals[i + 2] - f0);
    float s2 = s * s, s3 = s2 * s;
    return (2.f * s3 - 3.f * s2 + 1.f) * f0
         + (s3 - 2.f * s2 + s)         * d0
         + (-2.f * s3 + 3.f * s2)      * f1
         + (s3 - s2)                   * d1;
}

__global__ __launch_bounds__(256) void eik_kernel(
    const float* __restrict__ t_ptr,
    const float* __restrict__ psi_a,
    const float* __restrict__ theta_a,
    const float* __restrict__ varphi_a,
    const float* __restrict__ q_vals,
    const float* __restrict__ theta0_a,
    const float* __restrict__ omega_a,
    const float* __restrict__ psi0_a,
    const float* __restrict__ psi_scale_a,
    const float* __restrict__ alpha_scale_a,
    const float* __restrict__ gh_a,        // [M,4,6]
    const int*   __restrict__ n_a,
    float* __restrict__ out,               // [2*N]: phi then apar
    int N)
{
    const int gid   = blockIdx.x * blockDim.x + threadIdx.x;
    const int i0    = 2 * gid;
    if (i0 >= N) return;
    const bool full = (i0 + 1 < N);

    const float INV2PI = 0.15915494309189533577f;
    const float TWO_PI = 6.28318530717958647692f;
    const float NEXPC  = -0.72134752044448170368f; // -0.5*log2(e)

    const float t = t_ptr[0];

    v2f psi, theta, varphi;
    if (full) {
        psi    = ((const v2f*)psi_a)[gid];
        theta  = ((const v2f*)theta_a)[gid];
        varphi = ((const v2f*)varphi_a)[gid];
    } else {
        psi.x = psi.y = psi_a[i0];
        theta.x = theta.y = theta_a[i0];
        varphi.x = varphi.y = varphi_a[i0];
    }

    // cubic Hermite interp of q (alpha0 = q*theta0 + aoff analytically; aoff cancels in y)
    v2f q;
    q.x = cubic_q(q_vals, psi.x);
    q.y = cubic_q(q_vals, psi.y);

    const v2f q2pi = q * TWO_PI;
    const float tt = t * INV2PI;          // t in revolutions
    const v2f  v2p = varphi * INV2PI;     // varphi in revolutions

    v2f phi = (v2f)0.f, apar = (v2f)0.f;

    #pragma unroll 1
    for (int m = 0; m < MM; ++m) {
        // wave-uniform scalar loads
        const float theta0 = theta0_a[m];
        const float omega  = omega_a[m];
        const float psi0   = psi0_a[m];
        const float inv_ps = __builtin_amdgcn_rcpf(psi_scale_a[m]);
        const float inv_as = __builtin_amdgcn_rcpf(alpha_scale_a[m]);
        const float nf     = (float)n_a[m];
        const float* c     = gh_a + m * 24;

        const v2f x  = (psi - psi0) * inv_ps;
        const v2f x2 = x * x;
        const v2f x4 = 4.f * x2;

        // folded GH poly: p = (c0-2c3-2c5) + c1 x + c3(4x^2) + (c2+c4 x) y + c5(4y^2)
        v2f pa[4], pb[4];
        float pf[4];
        #pragma unroll
        for (int comp = 0; comp < 4; ++comp) {
            const float c0 = c[comp*6+0], c1 = c[comp*6+1], c2 = c[comp*6+2];
            const float c3 = c[comp*6+3], c4 = c[comp*6+4], c5 = c[comp*6+5];
            const float a0 = fmaf(-2.f, c3 + c5, c0);
            pa[comp] = VFMA((v2f)c3, x4, VFMA((v2f)c1, x, (v2f)a0));
            pb[comp] = VFMA((v2f)c4, x, (v2f)c2);
            pf[comp] = c5;
        }

        const v2f dth  = theta - theta0;
        const v2f qdth = q * dth;
        v2f y          = qdth * inv_as;          // y at k=0
        const v2f dy   = q2pi * inv_as;
        const v2f dphr = nf * q;                 // phase step / 2pi
        const v2f p0r  = VFMA((v2f)nf, qdth * INV2PI,
                              VFMA((v2f)omega, (v2f)tt, -nf * v2p));

        // seed trig (revolutions) + rotation recurrence over k
        v2f cp, sp, cd, sd;
        cp.x = COS_REV(p0r.x);  cp.y = COS_REV(p0r.y);
        sp.x = SIN_REV(p0r.x);  sp.y = SIN_REV(p0r.y);
        cd.x = COS_REV(dphr.x); cd.y = COS_REV(dphr.y);
        sd.x = SIN_REV(dphr.x); sd.y = SIN_REV(dphr.y);

        #pragma unroll
        for (int k = 0; k < KK; ++k) {
            const v2f t2 = VFMA(y, y, x2);            // x^2+y^2
            const v2f y4 = VFMA((v2f)4.f, t2, -x4);   // 4y^2
            const v2f ta = t2 * NEXPC;
            v2f g;
            g.x = EXP2F(ta.x);
            g.y = EXP2F(ta.y);
            const v2f gc = g * cp;
            const v2f gs = g * sp;
            const v2f p0 = VFMA((v2f)pf[0], y4, VFMA(pb[0], y, pa[0]));
            const v2f p1 = VFMA((v2f)pf[1], y4, VFMA(pb[1], y, pa[1]));
            const v2f p2 = VFMA((v2f)pf[2], y4, VFMA(pb[2], y, pa[2]));
            const v2f p3 = VFMA((v2f)pf[3], y4, VFMA(pb[3], y, pa[3]));
            phi  = VFMA(p0, gc, phi);
            phi  = VFMA(-p1, gs, phi);
            apar = VFMA(p2, gc, apar);
            apar = VFMA(-p3, gs, apar);
            if (k < KK - 1) {
                const v2f ncp = VFMA(cp, cd, -(sp * sd));
                const v2f nsp = VFMA(sp, cd,  cp * sd);
                cp = ncp; sp = nsp;
                y = y + dy;
            }
        }
    }

    if (full) {
        *(v2f*)(out + i0)     = phi;   // N even -> 8B aligned
        *(v2f*)(out + N + i0) = apar;
    } else {
        out[i0]     = phi.x;
        out[N + i0] = apar.x;
    }
}

extern "C" void kernel_launch(void* const* d_in, const int* in_sizes, int n_in,
                              void* d_out, int out_size, void* d_ws, size_t ws_size,
                              hipStream_t stream) {
    // 0:t 1:psi 2:theta 3:varphi 4:q_vals 5:aoff_vals 6:theta0 7:omega
    // 8:psi0 9:psi_scale 10:alpha_scale 11:gh_coefs 12:n
    const float* t       = (const float*)d_in[0];
    const float* psi     = (const float*)d_in[1];
    const float* theta   = (const float*)d_in[2];
    const float* varphi  = (const float*)d_in[3];
    const float* q_vals  = (const float*)d_in[4];
    const float* theta0  = (const float*)d_in[6];
    const float* omega   = (const float*)d_in[7];
    const float* psi0    = (const float*)d_in[8];
    const float* psc     = (const float*)d_in[9];
    const float* asc     = (const float*)d_in[10];
    const float* gh      = (const float*)d_in[11];
    const int*   n_arr   = (const int*)d_in[12];

    const int N = in_sizes[1];
    float* out = (float*)d_out;

    const int npair = (N + 1) / 2;
    const int block = 256;
    const int grid  = (npair + block - 1) / block;
    eik_kernel<<<grid, block, 0, stream>>>(t, psi, theta, varphi, q_vals,
                                           theta0, omega, psi0, psc, asc,
                                           gh, n_arr, out, N);
}